// Round 5
// baseline (825.811 us; speedup 1.0000x reference)
//
#include <hip/hip_runtime.h>
#include <cstddef>
#include <cstdint>

#define L_SEQ 2048
#define D_MODEL 2048
#define NH 16
#define DH 128
#define M_ROWS 4096   // B * L

// ---------------------------------------------------------------------------
// bf16 helpers (storage type: ushort)
// ---------------------------------------------------------------------------
__device__ __forceinline__ ushort f2bf(float f) {
    union { float f; uint32_t u; } v; v.f = f;
    const uint32_t u = v.u;
    return (ushort)((u + 0x7fffu + ((u >> 16) & 1u)) >> 16);   // RNE
}
__device__ __forceinline__ float bf2f(ushort h) {
    union { uint32_t u; float f; } v; v.u = ((uint32_t)h) << 16; return v.f;
}
__device__ __forceinline__ float2 bf2f2(uint32_t u) {
    union { uint32_t u; float f; } lo, hi;
    lo.u = u << 16; hi.u = u & 0xffff0000u;
    return make_float2(lo.f, hi.f);
}

__device__ __forceinline__ void gld_lds16(const void* g, void* l) {
    __builtin_amdgcn_global_load_lds(
        (const __attribute__((address_space(1))) void*)g,
        (__attribute__((address_space(3))) void*)l, 16, 0, 0);
}

typedef __bf16  bf16x8 __attribute__((ext_vector_type(8)));
typedef float   f32x4  __attribute__((ext_vector_type(4)));

// ---------------------------------------------------------------------------
// fp32 -> bf16 elementwise (8 elems/thread)
// ---------------------------------------------------------------------------
__global__ __launch_bounds__(256) void cvt_bf16(
    const float* __restrict__ in, ushort* __restrict__ out)
{
    const int i = (blockIdx.x * 256 + threadIdx.x) * 8;
    const float4 a = *(const float4*)&in[i];
    const float4 b = *(const float4*)&in[i + 4];
    uint4 o;
    o.x = (uint)f2bf(a.x) | ((uint)f2bf(a.y) << 16);
    o.y = (uint)f2bf(a.z) | ((uint)f2bf(a.w) << 16);
    o.z = (uint)f2bf(b.x) | ((uint)f2bf(b.y) << 16);
    o.w = (uint)f2bf(b.z) | ((uint)f2bf(b.w) << 16);
    *(uint4*)&out[i] = o;
}

// ---------------------------------------------------------------------------
// W [K,N] fp32 -> Wt [N,K] bf16 (32x32 LDS tile transpose)
// ---------------------------------------------------------------------------
__global__ __launch_bounds__(256) void transpose_cvt(
    const float* __restrict__ W, ushort* __restrict__ Wt, int K, int N)
{
    __shared__ float tile[32][33];
    const int n0 = blockIdx.x * 32, k0 = blockIdx.y * 32;
    const int t = threadIdx.x;
    const int r = t >> 3;          // 0..31
    const int c4 = (t & 7) * 4;    // 0..28
    const float4 v = *(const float4*)&W[(size_t)(k0 + r) * N + n0 + c4];
    tile[r][c4 + 0] = v.x; tile[r][c4 + 1] = v.y;
    tile[r][c4 + 2] = v.z; tile[r][c4 + 3] = v.w;
    __syncthreads();
    ushort4 o;
    o.x = f2bf(tile[c4 + 0][r]);
    o.y = f2bf(tile[c4 + 1][r]);
    o.z = f2bf(tile[c4 + 2][r]);
    o.w = f2bf(tile[c4 + 3][r]);
    *(ushort4*)&Wt[(size_t)(n0 + r) * K + k0 + c4] = o;
}

// ---------------------------------------------------------------------------
// RoPE cos/sin table: Rtab[l*64 + d] = {cos, sin}(l * 10000^(-d/64))
// ---------------------------------------------------------------------------
__global__ __launch_bounds__(256) void rope_table(float2* __restrict__ tab)
{
    const int i = blockIdx.x * 256 + threadIdx.x;   // 131072
    const int d = i & 63, l = i >> 6;
    const float inv = exp2f(-(float)d * 0.20762050593045857f); // log2(1e4)/64
    const float ang = (float)l * inv;
    float s, c;
    sincosf(ang, &s, &c);
    tab[i] = make_float2(c, s);
}

// ---------------------------------------------------------------------------
// K RoPE in-place on bf16 via table. One thread per (row, head, d-pair).
// ---------------------------------------------------------------------------
__global__ __launch_bounds__(256) void rope_k(
    ushort* __restrict__ T, const float2* __restrict__ tab)
{
    const int idx = blockIdx.x * 256 + threadIdx.x;  // 4096*16*32
    const int d2   = (idx & 31) * 2;
    const int head = (idx >> 5) & 15;
    const int row  = idx >> 9;
    const int l    = row & (L_SEQ - 1);
    const size_t base = (size_t)row * 2048 + head * 128 + d2;
    const uint a = *(const uint*)&T[base];
    const uint b = *(const uint*)&T[base + 64];
    const float2 t0 = bf2f2(a);   // d2, d2+1 (lo half)
    const float2 t1 = bf2f2(b);   // d2+64, d2+65
    const float2 cs0 = tab[l * 64 + d2];
    const float2 cs1 = tab[l * 64 + d2 + 1];
    const float o0x = t0.x * cs0.x - t1.x * cs0.y;
    const float o0y = t0.y * cs1.x - t1.y * cs1.y;
    const float o1x = t1.x * cs0.x + t0.x * cs0.y;
    const float o1y = t1.y * cs1.x + t0.y * cs1.y;
    *(uint*)&T[base]      = (uint)f2bf(o0x) | ((uint)f2bf(o0y) << 16);
    *(uint*)&T[base + 64] = (uint)f2bf(o1x) | ((uint)f2bf(o1y) << 16);
}

// ---------------------------------------------------------------------------
// bf16 MFMA GEMM (m97 recipe): C[M,N] = A[M,K] . Bt[N,K]^T
// MODE 0: f32 out ; MODE 1: bf16 out ; MODE 3: bf16 out transposed into
//   Vt[b][h][d][L] layout (rows = b*2048+l, cols = h*128+d), packed b64.
// ---------------------------------------------------------------------------
template <int MODE>
__global__ __launch_bounds__(256) void gemm_bf16(
    const ushort* __restrict__ A, const ushort* __restrict__ Bt,
    void* __restrict__ Cv, int M, int N, int K)
{
    __shared__ __align__(16) ushort As[128 * 32];
    __shared__ __align__(16) ushort Bs[128 * 32];
    const int bm = blockIdx.y * 128;
    const int bn = blockIdx.x * 128;
    const int t = threadIdx.x;
    const int w = t >> 6, lane = t & 63;
    const int wm = (w & 1) * 64;
    const int wn = (w >> 1) * 64;

    const int srow = t >> 2;
    const int scol = (t & 3) * 8;
    const ushort* Ag  = A  + (size_t)(bm + srow) * K + scol;
    const ushort* Ag2 = A  + (size_t)(bm + 64 + srow) * K + scol;
    const ushort* Bg  = Bt + (size_t)(bn + srow) * K + scol;
    const ushort* Bg2 = Bt + (size_t)(bn + 64 + srow) * K + scol;
    ushort* Asl  = &As[(size_t)t * 8];
    ushort* Asl2 = &As[(size_t)(t + 256) * 8];
    ushort* Bsl  = &Bs[(size_t)t * 8];
    ushort* Bsl2 = &Bs[(size_t)(t + 256) * 8];

    const int fr = lane & 15;
    const int fq = (lane >> 4) * 8;
    const ushort* Abase = &As[(size_t)(wm + fr) * 32 + fq];
    const ushort* Bbase = &Bs[(size_t)(wn + fr) * 32 + fq];

    f32x4 acc[4][4] = {};

    for (int k0 = 0; k0 < K; k0 += 32) {
        __syncthreads();
        gld_lds16(Ag + k0, Asl);
        gld_lds16(Ag2 + k0, Asl2);
        gld_lds16(Bg + k0, Bsl);
        gld_lds16(Bg2 + k0, Bsl2);
        __syncthreads();
        bf16x8 a[4], b[4];
        #pragma unroll
        for (int i = 0; i < 4; ++i) {
            a[i] = *(const bf16x8*)(Abase + (size_t)i * 16 * 32);
            b[i] = *(const bf16x8*)(Bbase + (size_t)i * 16 * 32);
        }
        #pragma unroll
        for (int mt = 0; mt < 4; ++mt)
            #pragma unroll
            for (int nt = 0; nt < 4; ++nt)
                acc[mt][nt] = __builtin_amdgcn_mfma_f32_16x16x32_bf16(
                    a[mt], b[nt], acc[mt][nt], 0, 0, 0);
    }

    const int crow = (lane >> 4) * 4;
    const int ccol = lane & 15;
    #pragma unroll
    for (int mt = 0; mt < 4; ++mt) {
        #pragma unroll
        for (int nt = 0; nt < 4; ++nt) {
            if (MODE == 3) {
                const size_t row = bm + wm + mt * 16 + crow;   // b*2048 + l
                const size_t col = bn + wn + nt * 16 + ccol;   // h*128 + d
                ushort4 o4;
                o4.x = f2bf(acc[mt][nt][0]); o4.y = f2bf(acc[mt][nt][1]);
                o4.z = f2bf(acc[mt][nt][2]); o4.w = f2bf(acc[mt][nt][3]);
                *(ushort4*)&((ushort*)Cv)[
                    ((row >> 11) * 16 + (col >> 7)) * (size_t)(128 * 2048)
                    + (col & 127) * 2048 + (row & 2047)] = o4;
            } else {
                #pragma unroll
                for (int reg = 0; reg < 4; ++reg) {
                    const size_t row = bm + wm + mt * 16 + crow + reg;
                    const size_t col = bn + wn + nt * 16 + ccol;
                    if (MODE == 1) {
                        ((ushort*)Cv)[row * N + col] = f2bf(acc[mt][nt][reg]);
                    } else {
                        ((float*)Cv)[row * N + col] = acc[mt][nt][reg];
                    }
                }
            }
        }
    }
}

// ---------------------------------------------------------------------------
// lam = sigmoid(x @ Wl + bl)
// ---------------------------------------------------------------------------
__global__ __launch_bounds__(256) void lam_kernel(
    const float* __restrict__ X, const float* __restrict__ Wl,
    const float* __restrict__ bl, float* __restrict__ Lam)
{
    const int idx = blockIdx.x * 256 + threadIdx.x;
    const int hh  = idx & 15;
    const int m   = idx >> 4;
    const float* xr = X + (size_t)m * D_MODEL;
    float acc = 0.0f;
    for (int d = 0; d < D_MODEL; d += 4) {
        const float4 xv = *(const float4*)&xr[d];
        acc += xv.x * Wl[(d + 0) * NH + hh];
        acc += xv.y * Wl[(d + 1) * NH + hh];
        acc += xv.z * Wl[(d + 2) * NH + hh];
        acc += xv.w * Wl[(d + 3) * NH + hh];
    }
    acc += bl[hh];
    Lam[idx] = 1.0f / (1.0f + expf(-acc));
}

// ---------------------------------------------------------------------------
// MFMA differential causal flash attention, v3.
// Grid: (16 pair-tiles, NH, B). Block: 256 thr = 4 waves = (p:2)x(slot:2).
// Each block processes q-tiles qt = 31-pt then qt = pt (33 key-tiles total).
// Wave handles 32 q-rows. K/V tiles loaded just-in-time (short register
// liveness -- v2's cross-phase prefetch registers caused scratch spills:
// 507 MB WRITE_SIZE). Q-RoPE fused into fragment load. exp2-domain softmax.
// ---------------------------------------------------------------------------
__global__ __launch_bounds__(256, 2) void attn_mfma(
    const ushort* __restrict__ Qb, const ushort* __restrict__ Kb,
    const ushort* __restrict__ Vtg, const float* __restrict__ Lam,
    const float2* __restrict__ Rtab, ushort* __restrict__ OutB)
{
    __shared__ __align__(16) ushort lds[27136];   // 54272 B
    ushort* K_sh  = lds;            // [64][136]
    ushort* Vt_sh = lds + 8704;     // [128][72]
    ushort* P_sh  = lds + 17920;    // 4 waves x [32][72]

    const int h  = blockIdx.y;
    const int b  = blockIdx.z;
    const int pt = blockIdx.x;
    const int t  = threadIdx.x;
    const int w = t >> 6, lane = t & 63;
    const int colL = lane & 15, quad = lane >> 4;
    const int p = w >> 1, slot = w & 1;
    ushort* Pw = P_sh + w * (32 * 72);

    const ushort* Kgbase = Kb  + (size_t)(b * 2048) * 2048 + h * 128;
    const ushort* Vgbase = Vtg + (size_t)((b * 16 + h) * 128) * 2048;
    const float scale2 = 0.12751744f;   // log2(e)/sqrt(128)

    for (int ph = 0; ph < 2; ++ph) {
        const int qt  = ph ? pt : 31 - pt;
        const int q0  = qt * 64;
        const int r0w = q0 + slot * 32;

        // ---- load Q frags + fused RoPE ----
        bf16x8 qf[2][4];
        #pragma unroll
        for (int g = 0; g < 2; ++g) {
            const int l = r0w + g * 16 + colL;
            const ushort* Qr = Qb + (size_t)(b * 2048 + l) * 4096
                             + (2 * h + p) * 128 + quad * 8;
            ushort raw[4][8];
            #pragma unroll
            for (int c = 0; c < 4; ++c)
                *(uint4*)raw[c] = *(const uint4*)&Qr[c * 32];
            const float2* tb = Rtab + l * 64 + quad * 8;
            ushort o[4][8];
            #pragma unroll
            for (int c = 0; c < 2; ++c)
                #pragma unroll
                for (int j = 0; j < 8; ++j) {
                    const float2 cs = tb[c * 32 + j];
                    const float a  = bf2f(raw[c][j]);
                    const float bb = bf2f(raw[c + 2][j]);
                    o[c][j]     = f2bf(a * cs.x - bb * cs.y);
                    o[c + 2][j] = f2bf(bb * cs.x + a * cs.y);
                }
            #pragma unroll
            for (int c = 0; c < 4; ++c)
                qf[g][c] = *(const bf16x8*)o[c];
        }

        f32x4 ctx[2][8] = {};
        float m2[2][4] = {{-1e30f,-1e30f,-1e30f,-1e30f},
                          {-1e30f,-1e30f,-1e30f,-1e30f}};
        float li[2][4] = {};

        for (int kt = 0; kt <= qt; ++kt) {
            const int kt0 = kt * 64;
            // just-in-time K/V tile load (short liveness - no spills)
            uint4 kvr[4], vvr[4];
            #pragma unroll
            for (int i = 0; i < 4; ++i) {
                const int c = t + i * 256;
                kvr[i] = *(const uint4*)&Kgbase[(size_t)(kt0 + (c >> 4)) * 2048 + (c & 15) * 8];
                vvr[i] = *(const uint4*)&Vgbase[(size_t)(c >> 3) * 2048 + kt0 + (c & 7) * 8];
            }
            __syncthreads();
            #pragma unroll
            for (int i = 0; i < 4; ++i) {
                const int c = t + i * 256;
                *(uint4*)&K_sh[(c >> 4) * 136 + (c & 15) * 8] = kvr[i];
                *(uint4*)&Vt_sh[(c >> 3) * 72 + (c & 7) * 8]  = vvr[i];
            }
            __syncthreads();

            // ---- QK^T: 32 rows x 64 keys ----
            f32x4 sc2[2][4] = {};
            #pragma unroll
            for (int c = 0; c < 4; ++c)
                #pragma unroll
                for (int nt = 0; nt < 4; ++nt) {
                    const bf16x8 kf = *(const bf16x8*)
                        &K_sh[(nt * 16 + colL) * 136 + c * 32 + quad * 8];
                    sc2[0][nt] = __builtin_amdgcn_mfma_f32_16x16x32_bf16(
                        qf[0][c], kf, sc2[0][nt], 0, 0, 0);
                    sc2[1][nt] = __builtin_amdgcn_mfma_f32_16x16x32_bf16(
                        qf[1][c], kf, sc2[1][nt], 0, 0, 0);
                }

            const bool dmask = (kt == qt);
            // ---- online softmax (exp2 domain) ----
            #pragma unroll
            for (int g = 0; g < 2; ++g)
                #pragma unroll
                for (int reg = 0; reg < 4; ++reg) {
                    const int row = r0w + g * 16 + quad * 4 + reg;
                    float s[4];
                    #pragma unroll
                    for (int nt = 0; nt < 4; ++nt) {
                        float v = sc2[g][nt][reg] * scale2;
                        if (dmask && (kt0 + nt * 16 + colL > row)) v = -1e9f;
                        s[nt] = v;
                    }
                    float mx = fmaxf(fmaxf(s[0], s[1]), fmaxf(s[2], s[3]));
                    #pragma unroll
                    for (int off = 8; off >= 1; off >>= 1)
                        mx = fmaxf(mx, __shfl_xor(mx, off));
                    const float mnew  = fmaxf(m2[g][reg], mx);
                    const float alpha = exp2f(m2[g][reg] - mnew);
                    float rs = 0.f;
                    #pragma unroll
                    for (int nt = 0; nt < 4; ++nt) {
                        const float pv = exp2f(s[nt] - mnew);
                        s[nt] = pv;
                        rs += pv;
                    }
                    #pragma unroll
                    for (int off = 8; off >= 1; off >>= 1)
                        rs += __shfl_xor(rs, off);
                    li[g][reg] = li[g][reg] * alpha + rs;
                    m2[g][reg] = mnew;
                    #pragma unroll
                    for (int nt2 = 0; nt2 < 8; ++nt2)
                        ctx[g][nt2][reg] *= alpha;
                    #pragma unroll
                    for (int nt = 0; nt < 4; ++nt)
                        Pw[(g * 16 + quad * 4 + reg) * 72 + nt * 16 + colL]
                            = f2bf(s[nt]);
                }

            // ---- PV ----
            #pragma unroll
            for (int c2 = 0; c2 < 2; ++c2) {
                const bf16x8 pf0 = *(const bf16x8*)
                    &Pw[colL * 72 + c2 * 32 + quad * 8];
                const bf16x8 pf1 = *(const bf16x8*)
                    &Pw[(16 + colL) * 72 + c2 * 32 + quad * 8];
                #pragma unroll
                for (int nt2 = 0; nt2 < 8; ++nt2) {
                    const bf16x8 vf = *(const bf16x8*)
                        &Vt_sh[(nt2 * 16 + colL) * 72 + c2 * 32 + quad * 8];
                    ctx[0][nt2] = __builtin_amdgcn_mfma_f32_16x16x32_bf16(
                        pf0, vf, ctx[0][nt2], 0, 0, 0);
                    ctx[1][nt2] = __builtin_amdgcn_mfma_f32_16x16x32_bf16(
                        pf1, vf, ctx[1][nt2], 0, 0, 0);
                }
            }
        }

        float invl[2][4];
        #pragma unroll
        for (int g = 0; g < 2; ++g)
            #pragma unroll
            for (int reg = 0; reg < 4; ++reg)
                invl[g][reg] = 1.0f / li[g][reg];

        // ---- differential combine through LDS ----
        float* comb = (float*)lds;   // [64][130] f32 (aliases K/Vt staging)
        __syncthreads();
        if (p == 1) {
            #pragma unroll
            for (int g = 0; g < 2; ++g)
                #pragma unroll
                for (int nt2 = 0; nt2 < 8; ++nt2)
                    #pragma unroll
                    for (int reg = 0; reg < 4; ++reg)
                        comb[(slot * 32 + g * 16 + quad * 4 + reg) * 130
                             + nt2 * 16 + colL] = ctx[g][nt2][reg] * invl[g][reg];
        }
        __syncthreads();
        if (p == 0) {
            #pragma unroll
            for (int g = 0; g < 2; ++g)
                #pragma unroll
                for (int reg = 0; reg < 4; ++reg) {
                    const int row = r0w + g * 16 + quad * 4 + reg;
                    const float lamv = Lam[(size_t)(b * 2048 + row) * 16 + h];
                    ushort* orow = OutB + (size_t)(b * 2048 + row) * 2048 + h * 128;
                    #pragma unroll
                    for (int nt2 = 0; nt2 < 8; ++nt2) {
                        const float c1 = comb[(slot * 32 + g * 16 + quad * 4 + reg) * 130
                                              + nt2 * 16 + colL];
                        const float o = ctx[g][nt2][reg] * invl[g][reg] - lamv * c1;
                        orow[nt2 * 16 + colL] = f2bf(o);
                    }
                }
        }
        __syncthreads();   // protect comb before next phase re-stages
    }
}

// ---------------------------------------------------------------------------
extern "C" void kernel_launch(void* const* d_in, const int* in_sizes, int n_in,
                              void* d_out, int out_size, void* d_ws, size_t ws_size,
                              hipStream_t stream)
{
    const float* x  = (const float*)d_in[0];
    const float* Wq = (const float*)d_in[1];
    const float* Wk = (const float*)d_in[2];
    const float* Wv = (const float*)d_in[3];
    const float* Wl = (const float*)d_in[4];
    const float* bl = (const float*)d_in[5];
    const float* Wo = (const float*)d_in[6];
    float* out = (float*)d_out;
    (void)ws_size; (void)in_sizes; (void)n_in; (void)out_size;

    ushort* ws   = (ushort*)d_ws;
    ushort* xb   = ws;                       // 4096x2048
    ushort* Qb16 = xb   + (size_t)8388608;   // 4096x4096
    ushort* Kb16 = Qb16 + (size_t)16777216;  // 4096x2048
    ushort* Vtg  = Kb16 + (size_t)8388608;   // 2x16x128x2048 (V^T)
    ushort* Wqt  = Vtg  + (size_t)8388608;   // 4096x2048 (Wq^T)
    ushort* Wkt  = Wqt  + (size_t)8388608;   // 2048x2048
    ushort* Wvt  = Wkt  + (size_t)4194304;   // 2048x2048
    ushort* Wot  = Wvt  + (size_t)4194304;   // 2048x2048
    ushort* OutB = Wot  + (size_t)4194304;   // 4096x2048
    float*  LamB = (float*)(OutB + (size_t)8388608);  // 4096x16
    float2* Rtab = (float2*)(LamB + (size_t)65536);   // 2048x64

    // dtype conversions + tables
    cvt_bf16<<<4096, 256, 0, stream>>>(x, xb);
    transpose_cvt<<<dim3(128, 64), 256, 0, stream>>>(Wq, Wqt, 2048, 4096);
    transpose_cvt<<<dim3(64, 64), 256, 0, stream>>>(Wk, Wkt, 2048, 2048);
    transpose_cvt<<<dim3(64, 64), 256, 0, stream>>>(Wv, Wvt, 2048, 2048);
    transpose_cvt<<<dim3(64, 64), 256, 0, stream>>>(Wo, Wot, 2048, 2048);
    lam_kernel<<<256, 256, 0, stream>>>(x, Wl, bl, LamB);
    rope_table<<<512, 256, 0, stream>>>(Rtab);

    // projections (bf16 MFMA); V written directly transposed
    gemm_bf16<1><<<dim3(32, 32), 256, 0, stream>>>(xb, Wqt, Qb16, M_ROWS, 4096, D_MODEL);
    gemm_bf16<1><<<dim3(16, 32), 256, 0, stream>>>(xb, Wkt, Kb16, M_ROWS, D_MODEL, D_MODEL);
    gemm_bf16<3><<<dim3(16, 32), 256, 0, stream>>>(xb, Wvt, Vtg, M_ROWS, D_MODEL, D_MODEL);

    // RoPE on K (Q RoPE fused in attention)
    rope_k<<<8192, 256, 0, stream>>>(Kb16, Rtab);

    // MFMA differential causal flash attention -> OutB (bf16)
    attn_mfma<<<dim3(16, NH, 2), 256, 0, stream>>>(Qb16, Kb16, Vtg, LamB, Rtab, OutB);

    // final projection (fp32 out)
    gemm_bf16<0><<<dim3(16, 32), 256, 0, stream>>>(OutB, Wot, out, M_ROWS, D_MODEL, D_MODEL);
}